// Round 1
// 1248.377 us; speedup vs baseline: 1.0521x; 1.0521x over previous
//
#include <hip/hip_runtime.h>

// DiscreteLayer (VQ-VAE quantize + EMA codebook stats), MI355X gfx950.
// x: [B=64, D=256, L=4096] fp32. embed: [D, K=32]. Outputs (flat concat):
//   quantize^T [B,D,L] (67108864 f32), embed_out [D,K] (8192), loss (1).
//
// V2: latency-bound -> streaming. Counters showed 580 GB/s (7% peak),
// VALU 6%, occupancy 21%: ~1 outstanding 256B request/wave. This version:
//  - stages x in 16x256 d-chunks via async global_load_lds (16B/lane,
//    1 KB/wave-instr), double-buffered, raw s_barrier + counted vmcnt(4)
//    so prefetch stays in flight across barriers (no __syncthreads drain).
//  - loss via identity: sum (q-f)^2 = best_c + ||f||^2 (xsq accumulated in
//    phase 1) -> phase 2 needs x only for the embed_sum scatter.
//  - quantize written as float4 (kstar exchanged through LDS).
//  - s_sum is a 2 KB per-chunk tile flushed per chunk -> 36 KB LDS/block
//    -> 4 blocks/CU (16 waves/CU).
//
// Argmin correctness unchanged: fp32 fast path; if (2nd - best) < GAP_THRESH,
// recompute c_k = ||e_k||^2 - 2 f.e_k in fp64 (exact products) -> matches
// fp64-reference argmin. First-occurrence tie order preserved (strict <).

constexpr int   Kc  = 32;
constexpr int   Dc  = 256;
constexpr int   Bc  = 64;
constexpr int   Lc  = 4096;
constexpr int   Nc  = Bc * Lc;               // 262144 points
constexpr long  QSIZE = (long)Bc * Dc * Lc;  // 67108864
constexpr float DECAYf = 0.99f;
constexpr float EPSf   = 1e-5f;
constexpr float GAP_THRESH = 0.02f;          // >> 2x fp32 c_k error (~6e-3)

constexpr int DCH = 16;                      // d-rows per staged chunk (16 KB)
constexpr int NCH = Dc / DCH;                // 16 chunks

// Workspace layout (floats):
//  [0]                      loss accumulator
//  [8 .. 8+NREP*K)          counts replicas
//  [512 .. 512+NREP*D*K)    embed_sum replicas
constexpr int WS_LOSS   = 0;
constexpr int WS_COUNTS = 8;
constexpr int WS_ESUM   = 512;
constexpr int NREP      = 8;
constexpr size_t WS_FLOATS = WS_ESUM + (size_t)NREP * Dc * Kc;

// Counted vmem wait: vmcnt(N) waits until <= N of this wave's vmem ops are
// outstanding (in-order retirement for loads; all our counted ops are
// global_load_lds). asm volatile + "memory" also fences compiler reordering.
#define WAITVM(N) asm volatile("s_waitcnt vmcnt(" #N ")" ::: "memory")

// Barrier WITHOUT the implicit vmcnt(0) drain that __syncthreads() emits.
// lgkmcnt(0) makes prior LDS writes visible; vmcnt handled via WAITVM.
__device__ __forceinline__ void bar() {
    asm volatile("s_waitcnt lgkmcnt(0)" ::: "memory");
    __builtin_amdgcn_s_barrier();
}

// Async global->LDS, 16 B per lane. LDS dest must be wave-uniform base +
// lane*16 -- our callers index LDS linearly by (q*256 + tid)*16, which is
// exactly (uniform per (q,wave)) + lane*16.
__device__ __forceinline__ void async_ld16(const float* g, float* l) {
    __builtin_amdgcn_global_load_lds(
        (const __attribute__((address_space(1))) void*)g,
        (__attribute__((address_space(3))) void*)l, 16, 0, 0);
}

// Stage chunk c (rows d = c*DCH .. +15, 256 cols) into sbuf[DCH][256].
// 4096 floats = 4 float4 per thread = 4 KB in flight per wave.
__device__ __forceinline__ void stage_chunk(const float* xt, int c,
                                            float* sbuf, int tid) {
    const float* g0 = xt + (size_t)(c * DCH) * Lc;
#pragma unroll
    for (int q = 0; q < 4; ++q) {
        const int i4 = q * 256 + tid;               // float4 index 0..1023
        async_ld16(g0 + (size_t)(i4 >> 6) * Lc + ((i4 & 63) << 2),
                   sbuf + (size_t)i4 * 4);
    }
}

__global__ __launch_bounds__(256, 4) void vq_main(
    const float* __restrict__ x, const float* __restrict__ embed,
    float* __restrict__ out_q, float* __restrict__ ws)
{
    __shared__ float  s_x[2][DCH][256];   // 32 KB double-buffered x chunk
    __shared__ float  s_sum[DCH * Kc];    // 2 KB per-chunk embed_sum tile
    __shared__ float  s_esq[Kc];
    __shared__ double s_esqd[Kc];
    __shared__ float  s_hist[Kc];
    __shared__ float  s_red[4];
    __shared__ int    s_k[256];

    const int tid = threadIdx.x;
    const int p0  = blockIdx.x * 256;     // block owns 256 consecutive points
    const int b   = p0 >> 12;             // 4096 points per b; 256 | 4096
    const int l0  = p0 & (Lc - 1);
    const float* xt = x + (size_t)b * Dc * Lc + l0;  // tile elem (d,ll) at xt[d*L+ll]

    // Kick off first stage immediately; init overlaps its latency.
    stage_chunk(xt, 0, &s_x[0][0][0], tid);

    for (int j = tid; j < DCH * Kc; j += 256) s_sum[j] = 0.f;
    if (tid < Kc) {
        s_hist[tid] = 0.f;
        double acc = 0.0;
        for (int d = 0; d < Dc; ++d) {
            double e = (double)embed[d * Kc + tid];
            acc = fma(e, e, acc);
        }
        s_esqd[tid] = acc;
        s_esq[tid]  = (float)acc;
    }

    // ---- Phase 1: dots vs all K codes from staged LDS chunks ----
    float dot[Kc];
#pragma unroll
    for (int k = 0; k < Kc; ++k) dot[k] = 0.f;
    float xsq = 0.f;                       // ||f||^2 for the loss identity

    for (int c = 0; c < NCH; ++c) {
        const int cb = c & 1;
        if (c + 1 < NCH) {
            stage_chunk(xt, c + 1, &s_x[cb ^ 1][0][0], tid);
            WAITVM(4);                     // chunk c landed; c+1 stays in flight
        } else {
            WAITVM(0);
        }
        bar();
        const float* er0 = embed + c * DCH * Kc;   // wave-uniform -> s_load
#pragma unroll
        for (int dd = 0; dd < DCH; ++dd) {
            const float f = s_x[cb][dd][tid];      // conflict-free (stride 1)
            xsq = fmaf(f, f, xsq);
            const float* er = er0 + dd * Kc;
#pragma unroll
            for (int k = 0; k < Kc; ++k) dot[k] = fmaf(f, er[k], dot[k]);
        }
        bar();                             // buffer free before re-stage
    }

    // argmin over c_k = ||e_k||^2 - 2 dot_k (first occurrence, strict <)
    int   kstar  = 0;
    float best   = 3.4e38f;
    float second = 3.4e38f;
#pragma unroll
    for (int k = 0; k < Kc; ++k) {
        float cc = fmaf(-2.0f, dot[k], s_esq[k]);
        if (cc < best)        { second = best; best = cc; kstar = k; }
        else if (cc < second) { second = cc; }
    }

    // Exact fp64 recompute for near-ties (rare; x column is L2/L3-hot)
    if (second - best < GAP_THRESH) {
        double bestd = 1e300;
        int kb = 0;
        for (int k = 0; k < Kc; ++k) {
            double acc = 0.0;
            for (int d = 0; d < Dc; ++d)
                acc = fma((double)xt[(size_t)d * Lc + tid],
                          (double)embed[d * Kc + k], acc);
            double cc = fma(-2.0, acc, s_esqd[k]);
            if (cc < bestd) { bestd = cc; kb = k; }
        }
        kstar = kb;
    }

    s_k[tid] = kstar;
    atomicAdd(&s_hist[kstar], 1.0f);

    // loss per point = best + ||f||^2  (== sum_d (q-f)^2 algebraically;
    // tie-flip discrepancy bounded by GAP_THRESH on ~1e-3 of points -> <1e-9
    // in the mean). Wave reduce -> block reduce -> one atomic per block.
    float lacc = best + xsq;
#pragma unroll
    for (int off = 32; off > 0; off >>= 1) lacc += __shfl_down(lacc, off);
    if ((tid & 63) == 0) s_red[tid >> 6] = lacc;
    bar();                                  // also publishes s_k, s_hist

    const int rep = blockIdx.x & (NREP - 1);
    if (tid == 0)
        atomicAdd(&ws[WS_LOSS], s_red[0] + s_red[1] + s_red[2] + s_red[3]);
    if (tid < Kc)
        atomicAdd(&ws[WS_COUNTS + rep * Kc + tid], s_hist[tid]);

    // ---- Phase 2: quantize float4-writes + embed_sum scatter, per chunk ----
    float* esum = ws + WS_ESUM + (size_t)rep * Dc * Kc;
    float* ot   = out_q + (size_t)b * Dc * Lc + l0;
    const int w    = tid >> 6;              // wave id 0..3
    const int lane = tid & 63;
    int k4[4];                              // this lane's 4 points' codes
#pragma unroll
    for (int t = 0; t < 4; ++t) k4[t] = s_k[(lane << 2) + t];

    for (int c = 0; c < NCH; ++c) {
        // re-stage chunk c (L2/L3-hot); quantize writes overlap the latency
        stage_chunk(xt, c, &s_x[0][0][0], tid);
#pragma unroll
        for (int j = 0; j < 4; ++j) {
            const int d = c * DCH + (j << 2) + w;        // rows w,w+4,w+8,w+12
            const float* erow = embed + d * Kc;          // 128 B row, L1-hot
            float4 q;
            q.x = erow[k4[0]];
            q.y = erow[k4[1]];
            q.z = erow[k4[2]];
            q.w = erow[k4[3]];
            *reinterpret_cast<float4*>(ot + (size_t)d * Lc + (lane << 2)) = q;
        }
        WAITVM(0);
        bar();
        // scatter this point's chunk values into s_sum (bank = kstar, ~2-way)
#pragma unroll
        for (int dd = 0; dd < DCH; ++dd)
            atomicAdd(&s_sum[dd * Kc + kstar], s_x[0][dd][tid]);
        bar();
        // flush 512-float tile to the global replica, rezero for next chunk
#pragma unroll
        for (int t = 0; t < 2; ++t) {
            const int j = (t << 8) + tid;                // j == dd*32 + k
            atomicAdd(&esum[(size_t)(c * DCH + (j >> 5)) * Kc + (j & 31)],
                      s_sum[j]);
            s_sum[j] = 0.f;
        }
        bar();
    }
}

__global__ void vq_finalize(
    const float* __restrict__ embed,
    const float* __restrict__ cluster_number,
    const float* __restrict__ embed_avg,
    const int*   __restrict__ training,
    const float* __restrict__ ws,
    float* __restrict__ out)
{
    const int j = blockIdx.x * 256 + threadIdx.x;   // 0 .. D*K-1
    if (j >= Dc * Kc) return;
    const int k = j & (Kc - 1);

    // cluster_number EMA + normalization constants (redundant per thread; tiny)
    float n = 0.f, cn_k = 0.f;
    for (int kk = 0; kk < Kc; ++kk) {
        float c = 0.f;
        for (int r = 0; r < NREP; ++r) c += ws[WS_COUNTS + r * Kc + kk];
        float cnew = DECAYf * cluster_number[kk] + (1.0f - DECAYf) * c;
        n += cnew;
        if (kk == k) cn_k = cnew;
    }
    float cn = (cn_k + EPSf) / (n + Kc * EPSf) * n;

    float s = 0.f;
    for (int r = 0; r < NREP; ++r) s += ws[WS_ESUM + (size_t)r * Dc * Kc + j];
    float avg = DECAYf * embed_avg[j] + (1.0f - DECAYf) * s;

    out[QSIZE + j] = (*training) ? (avg / cn) : embed[j];

    if (j == 0) {
        out[QSIZE + Dc * Kc] = ws[WS_LOSS] / (float)QSIZE;  // mean over B*L*D
    }
}

extern "C" void kernel_launch(void* const* d_in, const int* in_sizes, int n_in,
                              void* d_out, int out_size, void* d_ws, size_t ws_size,
                              hipStream_t stream)
{
    (void)in_sizes; (void)n_in; (void)out_size; (void)ws_size;
    const float* x              = (const float*)d_in[0];
    const float* embed          = (const float*)d_in[1];
    const float* cluster_number = (const float*)d_in[2];
    const float* embed_avg      = (const float*)d_in[3];
    const int*   training       = (const int*)d_in[4];
    float* out = (float*)d_out;
    float* ws  = (float*)d_ws;

    hipMemsetAsync(d_ws, 0, WS_FLOATS * sizeof(float), stream);
    vq_main<<<Nc / 256, 256, 0, stream>>>(x, embed, out, ws);
    vq_finalize<<<(Dc * Kc + 255) / 256, 256, 0, stream>>>(
        embed, cluster_number, embed_avg, training, ws, out);
}

// Round 3
// 628.290 us; speedup vs baseline: 2.0905x; 1.9869x over previous
//
#include <hip/hip_runtime.h>

// DiscreteLayer (VQ-VAE quantize + EMA codebook stats), MI355X gfx950.
// x: [B=64, D=256, L=4096] fp32. embed: [D, K=32]. Outputs (flat concat):
//   quantize^T [B,D,L] (67108864 f32), embed_out [D,K] (8192), loss (1).
//
// V3b: V3 with the compile fix (__builtin_nontemporal_store needs a native
// vector type, not HIP_vector_type). Theory unchanged from V3:
// V1->V2 (async staging) barely moved (1050->990us) => bottleneck is in
// what both shared: same-address atomic serialization under cluster skew.
//  - LDS atomic scatter replaced by ownership columns: s_acc[k][tid] += f,
//    column tid exclusively owned by thread tid -> non-atomic, skew-proof,
//    [32][257] padding -> conflict-free RMW and flush.
//  - esum global atomic contention cut by dynamic replica count (<=128,
//    floor 8 = proven-safe), chosen from ws_size at launch.
//  - fp64 tie recompute restricted to candidate codes (c_k <= best+GAP):
//    provably contains the exact argmin; ~6x cheaper tail.
//  - nontemporal quantize stores keep L2/L3 for the phase-2 restage.
//
// Argmin semantics: fp32 fast path; near-ties recomputed in fp64 (exact
// products) over the candidate set; first-occurrence order preserved.

constexpr int   Kc  = 32;
constexpr int   Dc  = 256;
constexpr int   Bc  = 64;
constexpr int   Lc  = 4096;
constexpr int   Nc  = Bc * Lc;               // 262144 points
constexpr long  QSIZE = (long)Bc * Dc * Lc;  // 67108864
constexpr float DECAYf = 0.99f;
constexpr float EPSf   = 1e-5f;
constexpr float GAP_THRESH = 0.02f;          // >> 2x fp32 c_k error (~6e-3)

constexpr int DCH = 16;                      // d-rows per staged chunk (16 KB)
constexpr int NCH = Dc / DCH;                // 16 chunks

typedef float f32x4 __attribute__((ext_vector_type(4)));

// Workspace layout (floats):
//  [0]                        loss accumulator
//  [8 .. 8+NREPC*K)           counts replicas (8 replicas, fixed)
//  [512 .. 512+nrep*D*K)      embed_sum replicas (nrep dynamic, power of 2)
constexpr int WS_LOSS   = 0;
constexpr int WS_COUNTS = 8;
constexpr int NREPC     = 8;
constexpr int WS_ESUM   = 512;

#define WAITVM(N) asm volatile("s_waitcnt vmcnt(" #N ")" ::: "memory")

// Barrier WITHOUT the implicit vmcnt(0) drain of __syncthreads().
__device__ __forceinline__ void bar() {
    asm volatile("s_waitcnt lgkmcnt(0)" ::: "memory");
    __builtin_amdgcn_s_barrier();
}

__device__ __forceinline__ void async_ld16(const float* g, float* l) {
    __builtin_amdgcn_global_load_lds(
        (const __attribute__((address_space(1))) void*)g,
        (__attribute__((address_space(3))) void*)l, 16, 0, 0);
}

// Stage chunk c (rows d = c*DCH..+15, 256 cols) into sbuf (linear [16][256]).
__device__ __forceinline__ void stage_chunk(const float* xt, int c,
                                            float* sbuf, int tid) {
    const float* g0 = xt + (size_t)(c * DCH) * Lc;
#pragma unroll
    for (int q = 0; q < 4; ++q) {
        const int i4 = q * 256 + tid;               // float4 index 0..1023
        async_ld16(g0 + (size_t)(i4 >> 6) * Lc + ((i4 & 63) << 2),
                   sbuf + (size_t)i4 * 4);
    }
}

// s_pool layout (floats):
//  [0,4096)       x stage buf0
//  [4096,8192)    x stage buf1 (phase 1 double-buffer only)
//  [4096,12320)   s_acc[32][257] (phase 2 only; overlays buf1)
constexpr int SACC    = 4096;
constexpr int SACC_LD = 257;                 // +1 pad: conflict-free flush
constexpr int POOLF   = SACC + Kc * SACC_LD; // 12320 floats = 49280 B

__global__ __launch_bounds__(256, 3) void vq_main(
    const float* __restrict__ x, const float* __restrict__ embed,
    float* __restrict__ out_q, float* __restrict__ ws, int nrep)
{
    __shared__ float  s_pool[POOLF];
    __shared__ float  s_esq[Kc];
    __shared__ double s_esqd[Kc];
    __shared__ float  s_hist[Kc];
    __shared__ float  s_red[4];
    __shared__ int    s_k[256];

    const int tid = threadIdx.x;
    const int p0  = blockIdx.x * 256;     // block owns 256 consecutive points
    const int b   = p0 >> 12;
    const int l0  = p0 & (Lc - 1);
    const float* xt = x + (size_t)b * Dc * Lc + l0;  // elem (d,ll) at xt[d*L+ll]

    stage_chunk(xt, 0, s_pool, tid);      // kick off; init overlaps latency

    if (tid < Kc) {
        s_hist[tid] = 0.f;
        double acc = 0.0;
        for (int d = 0; d < Dc; ++d) {
            double e = (double)embed[d * Kc + tid];
            acc = fma(e, e, acc);
        }
        s_esqd[tid] = acc;
        s_esq[tid]  = (float)acc;
    }

    // ---- Phase 1: dots vs all K codes from staged LDS chunks ----
    float dot[Kc];
#pragma unroll
    for (int k = 0; k < Kc; ++k) dot[k] = 0.f;
    float xsq = 0.f;

    for (int c = 0; c < NCH; ++c) {
        const int cb = c & 1;
        if (c + 1 < NCH) {
            stage_chunk(xt, c + 1, s_pool + (cb ^ 1) * 4096, tid);
            WAITVM(4);                    // chunk c landed; c+1 in flight
        } else {
            WAITVM(0);
        }
        bar();
        const float* er0 = embed + c * DCH * Kc;
        const float* sx  = s_pool + cb * 4096;
#pragma unroll
        for (int dd = 0; dd < DCH; ++dd) {
            const float f = sx[dd * 256 + tid];     // stride-1, conflict-free
            xsq = fmaf(f, f, xsq);
            const float* er = er0 + dd * Kc;
#pragma unroll
            for (int k = 0; k < Kc; ++k) dot[k] = fmaf(f, er[k], dot[k]);
        }
        bar();                            // buffer free before re-stage
    }

    // zero own s_acc column (overlays buf1; safe after final compute bar;
    // column tid is touched only by thread tid -> no barrier needed for RMW)
#pragma unroll
    for (int k = 0; k < Kc; ++k) s_pool[SACC + k * SACC_LD + tid] = 0.f;

    // argmin over c_k = ||e_k||^2 - 2 dot_k (first occurrence, strict <)
    int   kstar  = 0;
    float best   = 3.4e38f;
    float second = 3.4e38f;
#pragma unroll
    for (int k = 0; k < Kc; ++k) {
        float cc = fmaf(-2.0f, dot[k], s_esq[k]);
        if (cc < best)        { second = best; best = cc; kstar = k; }
        else if (cc < second) { second = cc; }
    }

    // fp64 recompute over the candidate set only. True argmin k* satisfies
    // cf_{k*} <= best + 2*err < best + GAP, so it is always evaluated; fp64
    // values are exact, ascending-k strict < preserves first-occurrence.
    if (second - best < GAP_THRESH) {
        const float lim = best + GAP_THRESH;
        double bestd = 1e300;
        int kb = 0;
        for (int k = 0; k < Kc; ++k) {
            float cf = fmaf(-2.0f, dot[k], s_esq[k]);
            if (__any(cf <= lim)) {
                double acc = 0.0;
                for (int d = 0; d < Dc; ++d)
                    acc = fma((double)xt[(size_t)d * Lc + tid],
                              (double)embed[d * Kc + k], acc);
                double cc = fma(-2.0, acc, s_esqd[k]);
                if (cc < bestd) { bestd = cc; kb = k; }
            }
        }
        kstar = kb;
    }

    s_k[tid] = kstar;
    atomicAdd(&s_hist[kstar], 1.0f);

    // loss per point = best + ||f||^2; wave->block reduce, 1 atomic/block
    float lacc = best + xsq;
#pragma unroll
    for (int off = 32; off > 0; off >>= 1) lacc += __shfl_down(lacc, off);
    if ((tid & 63) == 0) s_red[tid >> 6] = lacc;
    bar();                                // publishes s_k, s_hist, s_red

    const int repc = blockIdx.x & (NREPC - 1);
    if (tid == 0)
        atomicAdd(&ws[WS_LOSS], s_red[0] + s_red[1] + s_red[2] + s_red[3]);
    if (tid < Kc)
        atomicAdd(&ws[WS_COUNTS + repc * Kc + tid], s_hist[tid]);

    // ---- Phase 2: quantize stores + ownership-column embed_sum ----
    const int rep = blockIdx.x & (nrep - 1);
    float* esum = ws + WS_ESUM + (size_t)rep * Dc * Kc;
    float* ot   = out_q + (size_t)b * Dc * Lc + l0;
    const int w     = tid >> 6;           // wave id 0..3
    const int lane  = tid & 63;
    const int dd_own = tid >> 4;          // scatter row 0..15
    const int s_own  = tid & 15;          // scatter sub-column 0..15

    int k4[4];                            // codes for 2a's 4-col stores
#pragma unroll
    for (int t = 0; t < 4; ++t) k4[t] = s_k[(lane << 2) + t];
    int kk[16];                           // codes for 2b's point subset
#pragma unroll
    for (int j = 0; j < 16; ++j) kk[j] = s_k[j * 16 + s_own];

    float* s_acc = s_pool + SACC;

    for (int c = 0; c < NCH; ++c) {
        // restage chunk c into buf0 (L2/L3-hot); 2a stores cover the latency
        stage_chunk(xt, c, s_pool, tid);

        // 2a: quantize float4 stores (no x needed), nontemporal
#pragma unroll
        for (int j = 0; j < 4; ++j) {
            const int d = c * DCH + (j << 2) + w;
            const float* erow = embed + d * Kc;   // one 128B line, L1-hot
            f32x4 q;
            q.x = erow[k4[0]];
            q.y = erow[k4[1]];
            q.z = erow[k4[2]];
            q.w = erow[k4[3]];
            __builtin_nontemporal_store(
                q, reinterpret_cast<f32x4*>(ot + (size_t)d * Lc + (lane << 2)));
        }
        WAITVM(0);
        bar();

        // 2b: ownership scatter -- thread (dd_own, s_own) handles its 16
        // points; non-atomic RMW on exclusively-owned column tid.
#pragma unroll
        for (int j = 0; j < 16; ++j) {
            const float f = s_pool[dd_own * 256 + j * 16 + s_own];  // 4-way
            s_acc[kk[j] * SACC_LD + tid] += f;    // conflict ~2-way, no atomic
        }
        bar();

        // flush: thread sums 16 sub-columns for 2 (dd,k) cells, zeroes them.
        // banks: (kc + ddc*16 + s) % 32 -> distinct kc per lane => <=2-way.
#pragma unroll
        for (int t = 0; t < 2; ++t) {
            const int j2  = (t << 8) + tid;       // 0..511
            const int kc  = j2 & 31;
            const int ddc = j2 >> 5;
            float ssum = 0.f;
#pragma unroll
            for (int s = 0; s < 16; ++s) {
                float* cell = &s_acc[kc * SACC_LD + ddc * 16 + s];
                ssum += *cell;
                *cell = 0.f;                      // rezero for next chunk
            }
            atomicAdd(&esum[(size_t)(c * DCH + ddc) * Kc + kc], ssum);
        }
        bar();                                    // zeros visible before next 2b
    }
}

__global__ void vq_finalize(
    const float* __restrict__ embed,
    const float* __restrict__ cluster_number,
    const float* __restrict__ embed_avg,
    const int*   __restrict__ training,
    const float* __restrict__ ws,
    float* __restrict__ out, int nrep)
{
    const int j = blockIdx.x * 256 + threadIdx.x;   // 0 .. D*K-1
    if (j >= Dc * Kc) return;
    const int k = j & (Kc - 1);

    float n = 0.f, cn_k = 0.f;
    for (int kk = 0; kk < Kc; ++kk) {
        float c = 0.f;
        for (int r = 0; r < NREPC; ++r) c += ws[WS_COUNTS + r * Kc + kk];
        float cnew = DECAYf * cluster_number[kk] + (1.0f - DECAYf) * c;
        n += cnew;
        if (kk == k) cn_k = cnew;
    }
    float cn = (cn_k + EPSf) / (n + Kc * EPSf) * n;

    float s = 0.f;
    for (int r = 0; r < nrep; ++r) s += ws[WS_ESUM + (size_t)r * Dc * Kc + j];
    float avg = DECAYf * embed_avg[j] + (1.0f - DECAYf) * s;

    out[QSIZE + j] = (*training) ? (avg / cn) : embed[j];

    if (j == 0) {
        out[QSIZE + Dc * Kc] = ws[WS_LOSS] / (float)QSIZE;  // mean over B*L*D
    }
}

extern "C" void kernel_launch(void* const* d_in, const int* in_sizes, int n_in,
                              void* d_out, int out_size, void* d_ws, size_t ws_size,
                              hipStream_t stream)
{
    (void)in_sizes; (void)n_in; (void)out_size;
    const float* x              = (const float*)d_in[0];
    const float* embed          = (const float*)d_in[1];
    const float* cluster_number = (const float*)d_in[2];
    const float* embed_avg      = (const float*)d_in[3];
    const int*   training       = (const int*)d_in[4];
    float* out = (float*)d_out;
    float* ws  = (float*)d_ws;

    // embed_sum replica count: as many power-of-2 replicas as ws allows,
    // up to 128; floor 8 (= proven-safe V2 footprint, 264 KB).
    const size_t availf = ws_size / 4;
    int nrep = 8;
    while (nrep < 128 &&
           (size_t)WS_ESUM + (size_t)(nrep << 1) * Dc * Kc <= availf)
        nrep <<= 1;

    const size_t used = ((size_t)WS_ESUM + (size_t)nrep * Dc * Kc) * 4;
    (void)hipMemsetAsync(d_ws, 0, used, stream);
    vq_main<<<Nc / 256, 256, 0, stream>>>(x, embed, out, ws, nrep);
    vq_finalize<<<(Dc * Kc + 255) / 256, 256, 0, stream>>>(
        embed, cluster_number, embed_avg, training, ws, out, nrep);
}

// Round 4
// 588.343 us; speedup vs baseline: 2.2324x; 1.0679x over previous
//
#include <hip/hip_runtime.h>

// DiscreteLayer (VQ-VAE quantize + EMA codebook stats), MI355X gfx950.
// x: [B=64, D=256, L=4096] fp32. embed: [D, K=32]. Outputs (flat concat):
//   quantize^T [B,D,L] (67108864 f32), embed_out [D,K] (8192), loss (1).
//
// V4: V3b confirmed atomic-serialization theory (990->302us). Counters show
// nothing saturated (VALU 24%, HBM 24%, LDS ~60%) -> phase-2 LDS/barrier
// machinery is the remaining structure cost. Changes:
//  - phase-2 x restage -> direct per-thread float4 register loads (L3-hot,
//    fully coalesced 8x128B per instr). Removes stage, vmcnt(0) drain and
//    one barrier per chunk.
//  - codes packed as bytes (s_k8): 1 ds_read_b32 = 4 codes; 2b code reads
//    are wave-broadcast (same dword per 8 lanes).
//  - DCH2=32, 8 sub-columns -> flush per d-row halves; LDS ops/thread
//    1792 -> ~1050; barriers 48 -> 16.
//  - s_acc[32][257] overlays BOTH phase-1 buffers -> 33.7 KB LDS ->
//    4 blocks/CU (was 3).
//  - finalize: replica cap 64 + unroll (trims the ~60us nrep=128 tail).
//
// Argmin semantics: fp32 fast path; near-ties recomputed in fp64 (exact
// products) over candidate set; first-occurrence order preserved.

constexpr int   Kc  = 32;
constexpr int   Dc  = 256;
constexpr int   Bc  = 64;
constexpr int   Lc  = 4096;
constexpr int   Nc  = Bc * Lc;               // 262144 points
constexpr long  QSIZE = (long)Bc * Dc * Lc;  // 67108864
constexpr float DECAYf = 0.99f;
constexpr float EPSf   = 1e-5f;
constexpr float GAP_THRESH = 0.02f;          // >> 2x fp32 c_k error (~6e-3)

constexpr int DCH = 16;                      // phase-1 staged chunk rows
constexpr int NCH = Dc / DCH;                // 16 chunks
constexpr int DCH2 = 32;                     // phase-2 chunk rows
constexpr int NCH2 = Dc / DCH2;              // 8 chunks

typedef float f32x4 __attribute__((ext_vector_type(4)));

// Workspace layout (floats):
//  [0]                        loss accumulator
//  [8 .. 8+NREPC*K)           counts replicas (8 replicas, fixed)
//  [512 .. 512+nrep*D*K)      embed_sum replicas (nrep dynamic, power of 2)
constexpr int WS_LOSS   = 0;
constexpr int WS_COUNTS = 8;
constexpr int NREPC     = 8;
constexpr int WS_ESUM   = 512;

#define WAITVM(N) asm volatile("s_waitcnt vmcnt(" #N ")" ::: "memory")

// Barrier WITHOUT the implicit vmcnt(0) drain of __syncthreads().
__device__ __forceinline__ void bar() {
    asm volatile("s_waitcnt lgkmcnt(0)" ::: "memory");
    __builtin_amdgcn_s_barrier();
}

__device__ __forceinline__ void async_ld16(const float* g, float* l) {
    __builtin_amdgcn_global_load_lds(
        (const __attribute__((address_space(1))) void*)g,
        (__attribute__((address_space(3))) void*)l, 16, 0, 0);
}

// Stage chunk c (rows d = c*DCH..+15, 256 cols) into sbuf (linear [16][256]).
__device__ __forceinline__ void stage_chunk(const float* xt, int c,
                                            float* sbuf, int tid) {
    const float* g0 = xt + (size_t)(c * DCH) * Lc;
#pragma unroll
    for (int q = 0; q < 4; ++q) {
        const int i4 = q * 256 + tid;               // float4 index 0..1023
        async_ld16(g0 + (size_t)(i4 >> 6) * Lc + ((i4 & 63) << 2),
                   sbuf + (size_t)i4 * 4);
    }
}

// s_pool: phase 1 = dbuf [2][4096]; phase 2 = s_acc[32][257] (overlays both)
constexpr int SACC_LD = 257;                 // +1 pad: conflict-free flush
constexpr int POOLF   = Kc * SACC_LD;        // 8224 floats = 32.9 KB

__global__ __launch_bounds__(256, 4) void vq_main(
    const float* __restrict__ x, const float* __restrict__ embed,
    float* __restrict__ out_q, float* __restrict__ ws, int nrep)
{
    __shared__ float  s_pool[POOLF];
    __shared__ float  s_esq[Kc];
    __shared__ double s_esqd[Kc];
    __shared__ float  s_hist[Kc];
    __shared__ float  s_red[4];
    __shared__ unsigned char s_k8[256] __attribute__((aligned(4)));

    const int tid = threadIdx.x;
    const int p0  = blockIdx.x * 256;     // block owns 256 consecutive points
    const int b   = p0 >> 12;
    const int l0  = p0 & (Lc - 1);
    const float* xt = x + (size_t)b * Dc * Lc + l0;  // elem (d,ll) at xt[d*L+ll]

    stage_chunk(xt, 0, s_pool, tid);      // kick off; init overlaps latency

    if (tid < Kc) {
        s_hist[tid] = 0.f;
        double acc = 0.0;
        for (int d = 0; d < Dc; ++d) {
            double e = (double)embed[d * Kc + tid];
            acc = fma(e, e, acc);
        }
        s_esqd[tid] = acc;
        s_esq[tid]  = (float)acc;
    }

    // ---- Phase 1: dots vs all K codes from staged LDS chunks ----
    float dot[Kc];
#pragma unroll
    for (int k = 0; k < Kc; ++k) dot[k] = 0.f;
    float xsq = 0.f;

    for (int c = 0; c < NCH; ++c) {
        const int cb = c & 1;
        if (c + 1 < NCH) {
            stage_chunk(xt, c + 1, s_pool + (cb ^ 1) * 4096, tid);
            WAITVM(4);                    // chunk c landed; c+1 in flight
        } else {
            WAITVM(0);
        }
        bar();
        const float* er0 = embed + c * DCH * Kc;
        const float* sx  = s_pool + cb * 4096;
#pragma unroll
        for (int dd = 0; dd < DCH; ++dd) {
            const float f = sx[dd * 256 + tid];     // stride-1, conflict-free
            xsq = fmaf(f, f, xsq);
            const float* er = er0 + dd * Kc;
#pragma unroll
            for (int k = 0; k < Kc; ++k) dot[k] = fmaf(f, er[k], dot[k]);
        }
        bar();                            // buffer free before re-stage
    }

    // zero own s_acc column (overlays dbuf; safe after final compute bar;
    // column tid is touched only by thread tid -> no barrier needed for RMW)
#pragma unroll
    for (int k = 0; k < Kc; ++k) s_pool[k * SACC_LD + tid] = 0.f;

    // argmin over c_k = ||e_k||^2 - 2 dot_k (first occurrence, strict <)
    int   kstar  = 0;
    float best   = 3.4e38f;
    float second = 3.4e38f;
#pragma unroll
    for (int k = 0; k < Kc; ++k) {
        float cc = fmaf(-2.0f, dot[k], s_esq[k]);
        if (cc < best)        { second = best; best = cc; kstar = k; }
        else if (cc < second) { second = cc; }
    }

    // fp64 recompute over the candidate set only. True argmin k* satisfies
    // cf_{k*} <= best + 2*err < best + GAP, so it is always evaluated; fp64
    // values are exact, ascending-k strict < preserves first-occurrence.
    if (second - best < GAP_THRESH) {
        const float lim = best + GAP_THRESH;
        double bestd = 1e300;
        int kb = 0;
        for (int k = 0; k < Kc; ++k) {
            float cf = fmaf(-2.0f, dot[k], s_esq[k]);
            if (__any(cf <= lim)) {
                double acc = 0.0;
                for (int d = 0; d < Dc; ++d)
                    acc = fma((double)xt[(size_t)d * Lc + tid],
                              (double)embed[d * Kc + k], acc);
                double cc = fma(-2.0, acc, s_esqd[k]);
                if (cc < bestd) { bestd = cc; kb = k; }
            }
        }
        kstar = kb;
    }

    s_k8[tid] = (unsigned char)kstar;
    atomicAdd(&s_hist[kstar], 1.0f);

    // loss per point = best + ||f||^2; wave->block reduce, 1 atomic/block
    float lacc = best + xsq;
#pragma unroll
    for (int off = 32; off > 0; off >>= 1) lacc += __shfl_down(lacc, off);
    if ((tid & 63) == 0) s_red[tid >> 6] = lacc;
    bar();                                // publishes s_k8, s_hist, s_red

    const int repc = blockIdx.x & (NREPC - 1);
    if (tid == 0)
        atomicAdd(&ws[WS_LOSS], s_red[0] + s_red[1] + s_red[2] + s_red[3]);
    if (tid < Kc)
        atomicAdd(&ws[WS_COUNTS + repc * Kc + tid], s_hist[tid]);

    // ---- Phase 2: quantize NT stores + ownership-column embed_sum ----
    const int rep = blockIdx.x & (nrep - 1);
    float* esum = ws + WS_ESUM + (size_t)rep * Dc * Kc;
    float* ot   = out_q + (size_t)b * Dc * Lc + l0;
    const int w    = tid >> 6;            // wave id 0..3
    const int lane = tid & 63;
    const int dd   = tid >> 3;            // d-row within 32-row chunk (0..31)
    const int s    = tid & 7;             // sub-column 0..7

    // 2a codes: 4 consecutive points per lane (one dword of s_k8)
    const unsigned int k4dw =
        *reinterpret_cast<const unsigned int*>(s_k8 + 4 * lane);
    // 2b codes: this thread's 32 points {32*j4 + 4*s + u}, 8 dwords
    unsigned int kdw[8];
#pragma unroll
    for (int j4 = 0; j4 < 8; ++j4)
        kdw[j4] = *reinterpret_cast<const unsigned int*>(s_k8 + 32 * j4 + 4 * s);

    float* s_acc = s_pool;

    for (int c = 0; c < NCH2; ++c) {
        // 2a: quantize float4 NT stores for rows c*32 + j*4 + w (no x needed)
#pragma unroll
        for (int j = 0; j < 8; ++j) {
            const int d = c * DCH2 + (j << 2) + w;
            const float* erow = embed + d * Kc;   // one 128B line, L1-hot
            f32x4 q;
            q.x = erow[k4dw & 255];
            q.y = erow[(k4dw >> 8) & 255];
            q.z = erow[(k4dw >> 16) & 255];
            q.w = erow[k4dw >> 24];
            __builtin_nontemporal_store(
                q, reinterpret_cast<f32x4*>(ot + (size_t)d * Lc + (lane << 2)));
        }

        // 2b: direct register loads (L2/L3-hot, 8 lanes x 128B contiguous per
        // row) + exclusive-column RMW (no atomics, skew-proof)
        const float* xrow = xt + (size_t)(c * DCH2 + dd) * Lc;
#pragma unroll
        for (int j4 = 0; j4 < 8; ++j4) {
            const f32x4 v = *reinterpret_cast<const f32x4*>(
                xrow + (j4 << 5) + (s << 2));
            const unsigned int kw = kdw[j4];
            s_acc[(kw & 255)         * SACC_LD + tid] += v.x;
            s_acc[((kw >> 8) & 255)  * SACC_LD + tid] += v.y;
            s_acc[((kw >> 16) & 255) * SACC_LD + tid] += v.z;
            s_acc[(kw >> 24)         * SACC_LD + tid] += v.w;
        }
        bar();                            // scatter visible before flush

        // flush: 1024 cells (32 dd x 32 k) / 256 threads = 4 cells/thread;
        // cell (ddc,kc) = sum of 8 sub-columns. Banks: (kc + ddc*8 + s2)%32,
        // kc distinct per lane-half -> <=2-way.
#pragma unroll
        for (int i = 0; i < 4; ++i) {
            const int kc  = tid & 31;
            const int ddc = (i << 3) + (tid >> 5);
            float ssum = 0.f;
#pragma unroll
            for (int s2 = 0; s2 < 8; ++s2) {
                float* cell = &s_acc[kc * SACC_LD + (ddc << 3) + s2];
                ssum += *cell;
                *cell = 0.f;              // rezero for next chunk
            }
            atomicAdd(&esum[(size_t)(c * DCH2 + ddc) * Kc + kc], ssum);
        }
        bar();                            // zeros visible before next scatter
    }
}

__global__ void vq_finalize(
    const float* __restrict__ embed,
    const float* __restrict__ cluster_number,
    const float* __restrict__ embed_avg,
    const int*   __restrict__ training,
    const float* __restrict__ ws,
    float* __restrict__ out, int nrep)
{
    const int j = blockIdx.x * 256 + threadIdx.x;   // 0 .. D*K-1
    if (j >= Dc * Kc) return;
    const int k = j & (Kc - 1);

    float n = 0.f, cn_k = 0.f;
    for (int kk = 0; kk < Kc; ++kk) {
        float c = 0.f;
        for (int r = 0; r < NREPC; ++r) c += ws[WS_COUNTS + r * Kc + kk];
        float cnew = DECAYf * cluster_number[kk] + (1.0f - DECAYf) * c;
        n += cnew;
        if (kk == k) cn_k = cnew;
    }
    float cn = (cn_k + EPSf) / (n + Kc * EPSf) * n;

    float s = 0.f;
#pragma unroll 8
    for (int r = 0; r < nrep; ++r) s += ws[WS_ESUM + (size_t)r * Dc * Kc + j];
    float avg = DECAYf * embed_avg[j] + (1.0f - DECAYf) * s;

    out[QSIZE + j] = (*training) ? (avg / cn) : embed[j];

    if (j == 0) {
        out[QSIZE + Dc * Kc] = ws[WS_LOSS] / (float)QSIZE;  // mean over B*L*D
    }
}

extern "C" void kernel_launch(void* const* d_in, const int* in_sizes, int n_in,
                              void* d_out, int out_size, void* d_ws, size_t ws_size,
                              hipStream_t stream)
{
    (void)in_sizes; (void)n_in; (void)out_size;
    const float* x              = (const float*)d_in[0];
    const float* embed          = (const float*)d_in[1];
    const float* cluster_number = (const float*)d_in[2];
    const float* embed_avg      = (const float*)d_in[3];
    const int*   training       = (const int*)d_in[4];
    float* out = (float*)d_out;
    float* ws  = (float*)d_ws;

    // embed_sum replica count: power-of-2 replicas as ws allows, cap 64
    // (128 made vq_finalize's replica reduction a measurable tail);
    // floor 8 = proven-safe footprint.
    const size_t availf = ws_size / 4;
    int nrep = 8;
    while (nrep < 64 &&
           (size_t)WS_ESUM + (size_t)(nrep << 1) * Dc * Kc <= availf)
        nrep <<= 1;

    const size_t used = ((size_t)WS_ESUM + (size_t)nrep * Dc * Kc) * 4;
    (void)hipMemsetAsync(d_ws, 0, used, stream);
    vq_main<<<Nc / 256, 256, 0, stream>>>(x, embed, out, ws, nrep);
    vq_finalize<<<(Dc * Kc + 255) / 256, 256, 0, stream>>>(
        embed, cluster_number, embed_avg, training, ws, out, nrep);
}